// Round 8
// baseline (111.050 us; speedup 1.0000x reference)
//
#include <hip/hip_runtime.h>

#define T_LEN 16384
#define NSEC 6                   // order-5 butter = 3 SOS each (hp+lp)
#define NSTATE 12
#define NMAT (NSTATE * NSTATE)   // 144
#define NPOW 6                   // M^(2^i), i=0..5, M = A^64
#define NTHR 256                 // 1 signal per block; 4 waves
#define NS_TOT 2048

// (A^64)^(2^i), i=0..5, fp32 (built in fp64 by k_matpow).
__device__ float g_Mp[NPOW * NMAT];
// Phi(t) = C * A^t, t=0..63 (row vectors), fp32.
__device__ float g_Phi[64 * NSTATE];

__device__ __forceinline__ float rfl(float v) {
    return __int_as_float(__builtin_amdgcn_readfirstlane(__float_as_int(v)));
}

// ---------------------------------------------------------------------------
// Build one-step transition A (fp64); Phi(t)=C*A^t for t=0..63; then square
// 11 times storing A^(2^it), it=6..11 as Mp[it-6].
// ---------------------------------------------------------------------------
__global__ void k_matpow(const float* __restrict__ sos) {
    __shared__ double A[NMAT];
    __shared__ double ph[2][NSTATE];
    int tid = threadIdx.x;

    if (tid < NSTATE) {
        double b0[NSEC], b1[NSEC], b2[NSEC], a1[NSEC], a2[NSEC];
#pragma unroll
        for (int i = 0; i < NSEC; ++i) {
            b0[i] = (double)sos[i * 6 + 0];
            b1[i] = (double)sos[i * 6 + 1];
            b2[i] = (double)sos[i * 6 + 2];
            a1[i] = (double)sos[i * 6 + 4];
            a2[i] = (double)sos[i * 6 + 5];
        }
        double w1[NSEC], w2[NSEC];
#pragma unroll
        for (int i = 0; i < NSEC; ++i) {
            w1[i] = (tid == 2 * i) ? 1.0 : 0.0;
            w2[i] = (tid == 2 * i + 1) ? 1.0 : 0.0;
        }
        double cur = 0.0;   // zero input: unit-state probe, one step
#pragma unroll
        for (int i = 0; i < NSEC; ++i) {
            double yv = fma(b0[i], cur, w1[i]);
            double n1 = fma(b1[i], cur, fma(-a1[i], yv, w2[i]));
            double n2 = fma(b2[i], cur, -(a2[i] * yv));
            w1[i] = n1; w2[i] = n2; cur = yv;
        }
#pragma unroll
        for (int i = 0; i < NSEC; ++i) {
            A[(2 * i) * NSTATE + tid]     = w1[i];   // column tid
            A[(2 * i + 1) * NSTATE + tid] = w2[i];
        }
        // C row: y(zero input) = sum_i w1_i * prod_{j>i} b0_j ; w2 terms = 0
        double c = 0.0;
        if ((tid & 1) == 0) {
            int i = tid >> 1;
            double p = 1.0;
            for (int j = i + 1; j < NSEC; ++j) p *= (double)sos[j * 6 + 0];
            c = p;
        }
        ph[0][tid] = c;
    }
    __syncthreads();

    // Phi(t) = C * A^t, iterated row-vector x matrix (double-buffered)
    for (int t = 0; t < 64; ++t) {
        if (tid < NSTATE) {
            g_Phi[t * NSTATE + tid] = (float)ph[t & 1][tid];
            double v = 0.0;
#pragma unroll
            for (int kk = 0; kk < NSTATE; ++kk)
                v = fma(ph[t & 1][kk], A[kk * NSTATE + tid], v);
            ph[(t + 1) & 1][tid] = v;
        }
        __syncthreads();
    }

    const int rr = tid / NSTATE, cc = tid % NSTATE;
    for (int it = 1; it <= 11; ++it) {
        double v = 0.0;
        if (tid < NMAT) {
#pragma unroll
            for (int kk = 0; kk < NSTATE; ++kk)
                v = fma(A[rr * NSTATE + kk], A[kk * NSTATE + cc], v);
        }
        __syncthreads();
        if (tid < NMAT) {
            A[rr * NSTATE + cc] = v;
            if (it >= 6) g_Mp[(it - 6) * NMAT + tid] = (float)v;
        }
        __syncthreads();
    }
}

// ---------------------------------------------------------------------------
// One 256-thread block per signal. Thread t owns samples [t*64, t*64+64).
//   passA: zero-state filter; stash now holds y_zs (x consumed on the fly)
//   scan : 6-round wave-shuffle scan + one-barrier cross-wave decay fix
//   passB: y = y_zs + Phi(j) * s_in   (12 independent FMA/sample, LDS bcast)
//   write: 2 rounds x 32KB swizzled LDS staging -> coalesced global stores
// ---------------------------------------------------------------------------
__global__ void __launch_bounds__(NTHR, 4)
k_main(const float* __restrict__ x, const float* __restrict__ sos,
       float* __restrict__ y) {
    __shared__ float Mp[NPOW][NMAT];
    __shared__ float Ph[64 * NSTATE];
    __shared__ float cw[4][NSTATE];      // per-wave c at lane 63
    __shared__ float4 sm4[2048];         // 32KB write-stage buffer

    const int k = threadIdx.x;
    const int lane = k & 63;
    const int w = k >> 6;                // wave id 0..3
    const int sig = blockIdx.x;

    // stage scan matrices + Phi (overlaps pass A; barrier before scan)
    for (int i = k; i < NPOW * NMAT; i += NTHR)
        Mp[i / NMAT][i % NMAT] = g_Mp[i];
    for (int i = k; i < 64 * NSTATE; i += NTHR)
        Ph[i] = g_Phi[i];

    // coefficients -> SGPRs
    float b0[NSEC], b1[NSEC], b2[NSEC], a1[NSEC], a2[NSEC];
#pragma unroll
    for (int i = 0; i < NSEC; ++i) {
        b0[i] = rfl(sos[i * 6 + 0]);
        b1[i] = rfl(sos[i * 6 + 1]);
        b2[i] = rfl(sos[i * 6 + 2]);
        a1[i] = rfl(sos[i * 6 + 4]);
        a2[i] = rfl(sos[i * 6 + 5]);
    }

    // ---- pass A: zero-state filter; stash <- y_zs ----
    const float4* xp4 = (const float4*)(x + (size_t)sig * T_LEN) + k * 16;
    float4 stash[16];
    float w1_[NSEC], w2_[NSEC];
#pragma unroll
    for (int i = 0; i < NSEC; ++i) { w1_[i] = 0.f; w2_[i] = 0.f; }

    auto fstep = [&](float cur) -> float {
#pragma unroll
        for (int i = 0; i < NSEC; ++i) {
            float yv = fmaf(b0[i], cur, w1_[i]);
            w1_[i] = fmaf(b1[i], cur, fmaf(-a1[i], yv, w2_[i]));
            w2_[i] = fmaf(b2[i], cur, -(a2[i] * yv));
            cur = yv;
        }
        return cur;
    };

#pragma unroll
    for (int m = 0; m < 16; ++m) {
        float4 v = xp4[m];
        v.x = fstep(v.x); v.y = fstep(v.y); v.z = fstep(v.z); v.w = fstep(v.w);
        stash[m] = v;
    }
    float c0[NSTATE];
#pragma unroll
    for (int i = 0; i < NSEC; ++i) { c0[2 * i] = w1_[i]; c0[2 * i + 1] = w2_[i]; }

    __syncthreads();   // Mp/Ph staged

    // ---- wave-local inclusive scan: 6 shuffle rounds ----
#pragma unroll
    for (int rnd = 0; rnd < 6; ++rnd) {
        const int d = 1 << rnd;
        float pr[NSTATE];
#pragma unroll
        for (int j = 0; j < NSTATE; ++j) pr[j] = __shfl_up(c0[j], d, 64);
        if (lane >= d) {
            float nc[NSTATE];
#pragma unroll
            for (int q = 0; q < NSTATE; ++q) {
                float acc = c0[q];
#pragma unroll
                for (int kk = 0; kk < NSTATE; ++kk)
                    acc = fmaf(Mp[rnd][q * NSTATE + kk], pr[kk], acc);
                nc[q] = acc;
            }
#pragma unroll
            for (int j = 0; j < NSTATE; ++j) c0[j] = nc[j];
        }
    }

    if (lane == 63) {
#pragma unroll
        for (int j = 0; j < NSTATE; ++j) cw[w][j] = c0[j];
    }
    __syncthreads();

    // ---- cross-wave fix: c += M^(lane+1)*c63_prev (decay kills wave-2+) ----
    if (w > 0) {
        float v[NSTATE];
#pragma unroll
        for (int j = 0; j < NSTATE; ++j) v[j] = cw[w - 1][j];
#pragma unroll
        for (int i = 0; i < NPOW; ++i) {
            if (((lane + 1) >> i) & 1) {
                float nv[NSTATE];
#pragma unroll
                for (int q = 0; q < NSTATE; ++q) {
                    float acc = 0.f;
#pragma unroll
                    for (int kk = 0; kk < NSTATE; ++kk)
                        acc = fmaf(Mp[i][q * NSTATE + kk], v[kk], acc);
                    nv[q] = acc;
                }
#pragma unroll
                for (int j = 0; j < NSTATE; ++j) v[j] = nv[j];
            }
        }
        if (lane != 63) {   // lane 63 would need M^64 ~ 1e-12: drop
#pragma unroll
            for (int j = 0; j < NSTATE; ++j) c0[j] += v[j];
        }
    }

    // ---- seed state s_in = c_{k-1} ----
    float si[NSTATE];
#pragma unroll
    for (int j = 0; j < NSTATE; ++j) si[j] = __shfl_up(c0[j], 1, 64);
    if (lane == 0) {
#pragma unroll
        for (int j = 0; j < NSTATE; ++j) si[j] = (w == 0) ? 0.f : cw[w - 1][j];
    }

    // ---- pass B: y = y_zs + Phi(j) * s_in  (independent per sample) ----
#pragma unroll
    for (int m = 0; m < 16; ++m) {
        float4 v = stash[m];
        float corr[4];
#pragma unroll
        for (int q = 0; q < 4; ++q) {
            const float* ph = &Ph[(m * 4 + q) * NSTATE];
            float acc = 0.f;
#pragma unroll
            for (int kk = 0; kk < NSTATE; ++kk)
                acc = fmaf(ph[kk], si[kk], acc);
            corr[q] = acc;
        }
        v.x += corr[0]; v.y += corr[1]; v.z += corr[2]; v.w += corr[3];
        stash[m] = v;
    }

    // ---- write staging: 2 rounds x 32KB, swizzled, coalesced out ----
    float4* yp4 = (float4*)(y + (size_t)sig * T_LEN);
#pragma unroll 1
    for (int r = 0; r < 2; ++r) {
        __syncthreads();                 // reuse-safety between rounds
        if ((w >> 1) == r) {
            const int base = (w & 1) * 1024;
#pragma unroll
            for (int m = 0; m < 16; ++m)
                sm4[base + lane * 16 + (m ^ (lane & 15))] = stash[m];
        }
        __syncthreads();
#pragma unroll
        for (int q = 0; q < 8; ++q) {
            int j = k + 256 * q;                       // 0..2047
            int s = (j & ~15) | ((j ^ (j >> 4)) & 15); // matches writer swizzle
            yp4[r * 2048 + j] = sm4[s];
        }
    }
}

extern "C" void kernel_launch(void* const* d_in, const int* in_sizes, int n_in,
                              void* d_out, int out_size, void* d_ws, size_t ws_size,
                              hipStream_t stream) {
    const float* x   = (const float*)d_in[0];
    const float* sos = (const float*)d_in[1];
    if (n_in >= 2 && in_sizes[0] <= 256 && in_sizes[1] > 256) {  // insurance
        x = (const float*)d_in[1];
        sos = (const float*)d_in[0];
    }
    float* out = (float*)d_out;

    int NS = out_size / T_LEN;      // 2048 signals
    if (NS > NS_TOT) NS = NS_TOT;
    if (NS < 1) NS = 1;

    k_matpow<<<1, 256, 0, stream>>>(sos);
    k_main<<<NS, NTHR, 0, stream>>>(x, sos, out);
}

// Round 9
// 98.062 us; speedup vs baseline: 1.1325x; 1.1325x over previous
//
#include <hip/hip_runtime.h>

#define T_LEN 16384
#define NSEC 6                   // order-5 butter = 3 SOS each (hp+lp)
#define NSTATE 12
#define NMAT (NSTATE * NSTATE)   // 144
#define NPOW 5                   // M^(2^i), i=0..4, M = A^64 (M^31 max used)
#define NTHR 256                 // 1 signal per block; 4 waves
#define NS_TOT 2048

// (A^64)^(2^i), i=0..4, fp32 (built in fp64 by k_matpow).
__device__ float g_Mp[NPOW * NMAT];
// Phi(t) = C * A^t, t=0..63 (row vectors), fp32.
__device__ float g_Phi[64 * NSTATE];

__device__ __forceinline__ float rfl(float v) {
    return __int_as_float(__builtin_amdgcn_readfirstlane(__float_as_int(v)));
}

// ---------------------------------------------------------------------------
// Build one-step transition A (fp64); Phi(t)=C*A^t for t=0..63; square 10x,
// storing A^(2^it), it=6..10 as Mp[it-6] = (A^64)^(2^i), i=0..4.
// ---------------------------------------------------------------------------
__global__ void k_matpow(const float* __restrict__ sos) {
    __shared__ double A[NMAT];
    __shared__ double ph[2][NSTATE];
    int tid = threadIdx.x;

    if (tid < NSTATE) {
        double b0[NSEC], b1[NSEC], b2[NSEC], a1[NSEC], a2[NSEC];
#pragma unroll
        for (int i = 0; i < NSEC; ++i) {
            b0[i] = (double)sos[i * 6 + 0];
            b1[i] = (double)sos[i * 6 + 1];
            b2[i] = (double)sos[i * 6 + 2];
            a1[i] = (double)sos[i * 6 + 4];
            a2[i] = (double)sos[i * 6 + 5];
        }
        double w1[NSEC], w2[NSEC];
#pragma unroll
        for (int i = 0; i < NSEC; ++i) {
            w1[i] = (tid == 2 * i) ? 1.0 : 0.0;
            w2[i] = (tid == 2 * i + 1) ? 1.0 : 0.0;
        }
        double cur = 0.0;   // zero input: unit-state probe, one step
#pragma unroll
        for (int i = 0; i < NSEC; ++i) {
            double yv = fma(b0[i], cur, w1[i]);
            double n1 = fma(b1[i], cur, fma(-a1[i], yv, w2[i]));
            double n2 = fma(b2[i], cur, -(a2[i] * yv));
            w1[i] = n1; w2[i] = n2; cur = yv;
        }
#pragma unroll
        for (int i = 0; i < NSEC; ++i) {
            A[(2 * i) * NSTATE + tid]     = w1[i];   // column tid
            A[(2 * i + 1) * NSTATE + tid] = w2[i];
        }
        // C row: y(zero input) = sum_i w1_i * prod_{j>i} b0_j
        double c = 0.0;
        if ((tid & 1) == 0) {
            int i = tid >> 1;
            double p = 1.0;
            for (int j = i + 1; j < NSEC; ++j) p *= (double)sos[j * 6 + 0];
            c = p;
        }
        ph[0][tid] = c;
    }
    __syncthreads();

    // Phi(t) = C * A^t (row-vector iteration, double-buffered)
    for (int t = 0; t < 64; ++t) {
        if (tid < NSTATE) {
            g_Phi[t * NSTATE + tid] = (float)ph[t & 1][tid];
            double v = 0.0;
#pragma unroll
            for (int kk = 0; kk < NSTATE; ++kk)
                v = fma(ph[t & 1][kk], A[kk * NSTATE + tid], v);
            ph[(t + 1) & 1][tid] = v;
        }
        __syncthreads();
    }

    const int rr = tid / NSTATE, cc = tid % NSTATE;
    for (int it = 1; it <= 10; ++it) {
        double v = 0.0;
        if (tid < NMAT) {
#pragma unroll
            for (int kk = 0; kk < NSTATE; ++kk)
                v = fma(A[rr * NSTATE + kk], A[kk * NSTATE + cc], v);
        }
        __syncthreads();
        if (tid < NMAT) {
            A[rr * NSTATE + cc] = v;
            if (it >= 6) g_Mp[(it - 6) * NMAT + tid] = (float)v;
        }
        __syncthreads();
    }
}

// Triangular matvec macro body: out[q] = base + sum_{kk<=2*(q/2)+1} M[q][kk]*in[kk]
// (M block-lower-triangular; rows read as float4 from LDS, broadcast.)
#define TRI_MATVEC(MROW_BASE, IN, OUT, INIT_FROM)                               \
    {                                                                           \
        _Pragma("unroll")                                                       \
        for (int q = 0; q < NSTATE; ++q) {                                      \
            const int lim = 2 * (q >> 1) + 2;                                   \
            const float4* row = (const float4*)((MROW_BASE) + q * NSTATE);      \
            float acc = (INIT_FROM);                                            \
            float4 r0 = row[0];                                                 \
            acc = fmaf(r0.x, (IN)[0], acc);                                     \
            acc = fmaf(r0.y, (IN)[1], acc);                                     \
            if (lim > 2) { acc = fmaf(r0.z, (IN)[2], acc);                      \
                           acc = fmaf(r0.w, (IN)[3], acc); }                    \
            if (lim > 4) {                                                      \
                float4 r1 = row[1];                                             \
                acc = fmaf(r1.x, (IN)[4], acc);                                 \
                acc = fmaf(r1.y, (IN)[5], acc);                                 \
                if (lim > 6) { acc = fmaf(r1.z, (IN)[6], acc);                  \
                               acc = fmaf(r1.w, (IN)[7], acc); }                \
            }                                                                   \
            if (lim > 8) {                                                      \
                float4 r2 = row[2];                                             \
                acc = fmaf(r2.x, (IN)[8], acc);                                 \
                acc = fmaf(r2.y, (IN)[9], acc);                                 \
                if (lim > 10) { acc = fmaf(r2.z, (IN)[10], acc);                \
                                acc = fmaf(r2.w, (IN)[11], acc); }              \
            }                                                                   \
            (OUT)[q] = acc;                                                     \
        }                                                                       \
    }

// ---------------------------------------------------------------------------
// One 256-thread block per signal. Thread t owns samples [t*64, t*64+64).
// ---------------------------------------------------------------------------
__global__ void __launch_bounds__(NTHR, 4)
k_main(const float* __restrict__ x, const float* __restrict__ sos,
       float* __restrict__ y) {
    __shared__ float Mp[NPOW][NMAT];     // 2.88 KB (rows 48B, f4-aligned)
    __shared__ float Ph[64 * NSTATE];    // 3 KB
    __shared__ float cw[4][NSTATE];      // per-wave c at lane 63
    __shared__ float4 sm4[2048];         // 32 KB write-stage buffer

    const int k = threadIdx.x;
    const int lane = k & 63;
    const int w = k >> 6;                // wave id 0..3
    const int sig = blockIdx.x;

    // stage scan matrices + Phi (overlaps pass A; barrier before scan)
    for (int i = k; i < NPOW * NMAT; i += NTHR)
        Mp[i / NMAT][i % NMAT] = g_Mp[i];
    for (int i = k; i < 64 * NSTATE; i += NTHR)
        Ph[i] = g_Phi[i];

    // coefficients -> SGPRs
    float b0[NSEC], b1[NSEC], b2[NSEC], a1[NSEC], a2[NSEC];
#pragma unroll
    for (int i = 0; i < NSEC; ++i) {
        b0[i] = rfl(sos[i * 6 + 0]);
        b1[i] = rfl(sos[i * 6 + 1]);
        b2[i] = rfl(sos[i * 6 + 2]);
        a1[i] = rfl(sos[i * 6 + 4]);
        a2[i] = rfl(sos[i * 6 + 5]);
    }

    // ---- pass A: zero-state filter; stash <- y_zs ----
    const float4* xp4 = (const float4*)(x + (size_t)sig * T_LEN) + k * 16;
    float4 stash[16];
    float w1_[NSEC], w2_[NSEC];
#pragma unroll
    for (int i = 0; i < NSEC; ++i) { w1_[i] = 0.f; w2_[i] = 0.f; }

    auto fstep = [&](float cur) -> float {
#pragma unroll
        for (int i = 0; i < NSEC; ++i) {
            float yv = fmaf(b0[i], cur, w1_[i]);
            w1_[i] = fmaf(b1[i], cur, fmaf(-a1[i], yv, w2_[i]));
            w2_[i] = fmaf(b2[i], cur, -(a2[i] * yv));
            cur = yv;
        }
        return cur;
    };

#pragma unroll
    for (int m = 0; m < 16; ++m) {
        float4 v = xp4[m];
        v.x = fstep(v.x); v.y = fstep(v.y); v.z = fstep(v.z); v.w = fstep(v.w);
        stash[m] = v;
    }
    float c0[NSTATE];
#pragma unroll
    for (int i = 0; i < NSEC; ++i) { c0[2 * i] = w1_[i]; c0[2 * i + 1] = w2_[i]; }

    __syncthreads();   // Mp/Ph staged

    // ---- wave-local inclusive scan: 5 shuffle rounds (window 32, decay-safe) ----
#pragma unroll
    for (int rnd = 0; rnd < NPOW; ++rnd) {
        const int d = 1 << rnd;
        float pr[NSTATE];
#pragma unroll
        for (int j = 0; j < NSTATE; ++j) pr[j] = __shfl_up(c0[j], d, 64);
        if (lane >= d) {
            float nc[NSTATE];
            TRI_MATVEC(Mp[rnd], pr, nc, c0[q]);
#pragma unroll
            for (int j = 0; j < NSTATE; ++j) c0[j] = nc[j];
        }
    }

    if (lane == 63) {
#pragma unroll
        for (int j = 0; j < NSTATE; ++j) cw[w][j] = c0[j];
    }
    __syncthreads();

    // ---- cross-wave fix: c += M^(lane+1)*T_prev, lanes 0..30 (decay beyond) ----
    if (w > 0) {
        float v[NSTATE];
#pragma unroll
        for (int j = 0; j < NSTATE; ++j) v[j] = cw[w - 1][j];
#pragma unroll
        for (int i = 0; i < NPOW; ++i) {
            if (((lane + 1) >> i) & 1) {
                float nv[NSTATE];
                TRI_MATVEC(Mp[i], v, nv, 0.f);
#pragma unroll
                for (int j = 0; j < NSTATE; ++j) v[j] = nv[j];
            }
        }
        if (lane < 31) {
#pragma unroll
            for (int j = 0; j < NSTATE; ++j) c0[j] += v[j];
        }
    }

    // ---- seed state s_in = c_{lane-1} (lane 0: T_prev) ----
    float si[NSTATE];
#pragma unroll
    for (int j = 0; j < NSTATE; ++j) si[j] = __shfl_up(c0[j], 1, 64);
    if (lane == 0) {
#pragma unroll
        for (int j = 0; j < NSTATE; ++j) si[j] = (w == 0) ? 0.f : cw[w - 1][j];
    }

    // ---- pass B: y = y_zs + Phi(j)*s_in (full rows, float4 LDS reads) ----
#pragma unroll
    for (int m = 0; m < 16; ++m) {
        float4 v = stash[m];
        float corr[4];
#pragma unroll
        for (int q = 0; q < 4; ++q) {
            const float4* ph = (const float4*)&Ph[(m * 4 + q) * NSTATE];
            float4 p0 = ph[0], p1 = ph[1], p2 = ph[2];
            float acc = p0.x * si[0];
            acc = fmaf(p0.y, si[1], acc);
            acc = fmaf(p0.z, si[2], acc);
            acc = fmaf(p0.w, si[3], acc);
            acc = fmaf(p1.x, si[4], acc);
            acc = fmaf(p1.y, si[5], acc);
            acc = fmaf(p1.z, si[6], acc);
            acc = fmaf(p1.w, si[7], acc);
            acc = fmaf(p2.x, si[8], acc);
            acc = fmaf(p2.y, si[9], acc);
            acc = fmaf(p2.z, si[10], acc);
            acc = fmaf(p2.w, si[11], acc);
            corr[q] = acc;
        }
        v.x += corr[0]; v.y += corr[1]; v.z += corr[2]; v.w += corr[3];
        stash[m] = v;
    }

    // ---- write staging: 2 rounds x 32KB, swizzled, coalesced out ----
    float4* yp4 = (float4*)(y + (size_t)sig * T_LEN);
#pragma unroll 1
    for (int r = 0; r < 2; ++r) {
        __syncthreads();
        if ((w >> 1) == r) {
            const int base = (w & 1) * 1024;
#pragma unroll
            for (int m = 0; m < 16; ++m)
                sm4[base + lane * 16 + (m ^ (lane & 15))] = stash[m];
        }
        __syncthreads();
#pragma unroll
        for (int q = 0; q < 8; ++q) {
            int j = k + 256 * q;                       // 0..2047
            int s = (j & ~15) | ((j ^ (j >> 4)) & 15); // matches writer swizzle
            yp4[r * 2048 + j] = sm4[s];
        }
    }
}

extern "C" void kernel_launch(void* const* d_in, const int* in_sizes, int n_in,
                              void* d_out, int out_size, void* d_ws, size_t ws_size,
                              hipStream_t stream) {
    const float* x   = (const float*)d_in[0];
    const float* sos = (const float*)d_in[1];
    if (n_in >= 2 && in_sizes[0] <= 256 && in_sizes[1] > 256) {  // insurance
        x = (const float*)d_in[1];
        sos = (const float*)d_in[0];
    }
    float* out = (float*)d_out;

    int NS = out_size / T_LEN;      // 2048 signals
    if (NS > NS_TOT) NS = NS_TOT;
    if (NS < 1) NS = 1;

    k_matpow<<<1, 256, 0, stream>>>(sos);
    k_main<<<NS, NTHR, 0, stream>>>(x, sos, out);
}